// Round 2
// baseline (1381.856 us; speedup 1.0000x reference)
//
#include <hip/hip_runtime.h>
#include <cstdint>
#include <cstddef>

typedef unsigned short ushort_t;
typedef __attribute__((ext_vector_type(8))) __bf16 bf16x8;
typedef __attribute__((ext_vector_type(8))) short  s16x8;
typedef __attribute__((ext_vector_type(4))) float  f32x4;

#define NE 8
#define DIM 1024
#define HIDDEN 4096
#define NTOK 8192
#define CAP NTOK              // max rows per expert
#define NROWS (NTOK * 2)      // total routed rows = 16384

#define BM 128
#define BN 64
#define BK 32
#define LDP 40                // padded LDS row length (bf16 elems): 80B, 16B-aligned

// ---------------- workspace layout (bytes) ----------------
static constexpr size_t WS_COUNTS  = 0;                                 // NE ints
static constexpr size_t WS_OFFSETS = 256;                               // NE ints
static constexpr size_t WS_TOKENS  = 512;                               // NE*CAP ints
static constexpr size_t WS_WEIGHTS = WS_TOKENS + (size_t)NE * CAP * 4;  // NE*CAP floats
static constexpr size_t WS_H       = ((WS_WEIGHTS + (size_t)NE * CAP * 4 + 1023) / 1024) * 1024;
// h: NROWS * HIDDEN bf16 = 128 MiB; total ws ~= 134.8 MB

// ---------------- helpers ----------------
__device__ __forceinline__ ushort_t cvt_bf16(float f) {
  unsigned u = __float_as_uint(f);
  return (ushort_t)((u + 0x7FFFu + ((u >> 16) & 1u)) >> 16);
}

__device__ __forceinline__ void st8(ushort_t* dst, float4 a, float4 b) {
  s16x8 v;
  v[0] = (short)cvt_bf16(a.x); v[1] = (short)cvt_bf16(a.y);
  v[2] = (short)cvt_bf16(a.z); v[3] = (short)cvt_bf16(a.w);
  v[4] = (short)cvt_bf16(b.x); v[5] = (short)cvt_bf16(b.y);
  v[6] = (short)cvt_bf16(b.z); v[7] = (short)cvt_bf16(b.w);
  *reinterpret_cast<s16x8*>(dst) = v;
}

__device__ __forceinline__ bf16x8 ldb(const ushort_t* p) {
  union { s16x8 s; bf16x8 b; } u;
  u.s = *reinterpret_cast<const s16x8*>(p);
  return u.b;
}

__device__ __forceinline__ f32x4 mfma16(bf16x8 a, bf16x8 b, f32x4 c) {
  return __builtin_amdgcn_mfma_f32_16x16x32_bf16(a, b, c, 0, 0, 0);
}

// ---------------- gating: wave per token ----------------
__global__ __launch_bounds__(256) void gating_kernel(
    const float* __restrict__ x, const float* __restrict__ wg,
    const float* __restrict__ bg, int* __restrict__ counts,
    int* __restrict__ token_list, float* __restrict__ weight_list) {
  int gid  = blockIdx.x * blockDim.x + threadIdx.x;
  int tok  = gid >> 6;
  int lane = threadIdx.x & 63;
  if (tok >= NTOK) return;
  const float* xr = x + (size_t)tok * DIM;

  float part[NE];
#pragma unroll
  for (int e = 0; e < NE; ++e) part[e] = 0.f;
  for (int i = lane; i < DIM; i += 64) {
    float xv = xr[i];
#pragma unroll
    for (int e = 0; e < NE; ++e) part[e] = fmaf(xv, wg[e * DIM + i], part[e]);
  }
#pragma unroll
  for (int e = 0; e < NE; ++e) {
    float v = part[e];
#pragma unroll
    for (int o = 32; o > 0; o >>= 1) v += __shfl_xor(v, o, 64);
    part[e] = v + bg[e];
  }
  if (lane == 0) {
    int i0 = 0; float v0 = part[0];
#pragma unroll
    for (int e = 1; e < NE; ++e) if (part[e] > v0) { v0 = part[e]; i0 = e; }
    int i1 = -1; float v1 = -INFINITY;
#pragma unroll
    for (int e = 0; e < NE; ++e) if (e != i0 && part[e] > v1) { v1 = part[e]; i1 = e; }
    float e1 = expf(v1 - v0);
    float s  = 1.f + e1;
    float w0 = 1.f / s;
    float w1 = e1 / s;
    int s0 = atomicAdd(&counts[i0], 1);
    token_list[i0 * CAP + s0]  = tok;
    weight_list[i0 * CAP + s0] = w0;
    int s1 = atomicAdd(&counts[i1], 1);
    token_list[i1 * CAP + s1]  = tok;
    weight_list[i1 * CAP + s1] = w1;
  }
}

// ---------------- tiny prefix sum ----------------
__global__ void prefix_kernel(const int* __restrict__ counts, int* __restrict__ offsets) {
  if (threadIdx.x == 0) {
    int acc = 0;
    for (int e = 0; e < NE; ++e) { offsets[e] = acc; acc += counts[e]; }
  }
}

// ---------------- stage 1: h = silu(X Wg^T) * (X Wu^T), grouped, bf16 MFMA ----------------
__global__ __launch_bounds__(256) void stage1_kernel(
    const float* __restrict__ x, const float* __restrict__ Wgate,
    const float* __restrict__ Wup, const int* __restrict__ counts,
    const int* __restrict__ offsets, const int* __restrict__ token_list,
    ushort_t* __restrict__ h) {
  const int e  = blockIdx.z;
  const int mt = blockIdx.y;
  const int nt = blockIdx.x;
  const int count = counts[e];
  if (mt * BM >= count) return;

  __shared__ __align__(16) ushort_t Xs[BM][LDP];
  __shared__ __align__(16) ushort_t Gs[BN][LDP];
  __shared__ __align__(16) ushort_t Us[BN][LDP];
  __shared__ int toks[BM];

  const int t = threadIdx.x;
  if (t < BM) {
    int m = mt * BM + t;
    toks[t] = token_list[e * CAP + (m < count ? m : count - 1)];
  }
  __syncthreads();

  const float* Wg = Wgate + (size_t)e * HIDDEN * DIM + (size_t)(nt * BN) * DIM;
  const float* Wu = Wup   + (size_t)e * HIDDEN * DIM + (size_t)(nt * BN) * DIM;

  const int wid  = t >> 6;
  const int lane = t & 63;
  const int wm   = wid & 1;      // 0..1 : 64-row half
  const int wn   = wid >> 1;     // 0..1 : 32-col half
  const int fr   = lane & 15;
  const int kg   = lane >> 4;

  f32x4 accg[4][2], accu[4][2];
#pragma unroll
  for (int i = 0; i < 4; ++i)
#pragma unroll
    for (int j = 0; j < 2; ++j) { accg[i][j] = (f32x4)0.f; accu[i][j] = (f32x4)0.f; }

  const int sr = t >> 2;         // 0..63
  const int sc = (t & 3) * 8;    // 0,8,16,24

  const int tok0 = toks[sr];
  const int tok1 = toks[sr + 64];
  const float* xp0 = x + (size_t)tok0 * DIM + sc;
  const float* xp1 = x + (size_t)tok1 * DIM + sc;
  const float* gp  = Wg + (size_t)sr * DIM + sc;
  const float* up  = Wu + (size_t)sr * DIM + sc;

  for (int k0 = 0; k0 < DIM; k0 += BK) {
    float4 a0 = *reinterpret_cast<const float4*>(xp0 + k0);
    float4 a1 = *reinterpret_cast<const float4*>(xp0 + k0 + 4);
    float4 b0 = *reinterpret_cast<const float4*>(xp1 + k0);
    float4 b1 = *reinterpret_cast<const float4*>(xp1 + k0 + 4);
    float4 g0 = *reinterpret_cast<const float4*>(gp + k0);
    float4 g1 = *reinterpret_cast<const float4*>(gp + k0 + 4);
    float4 u0 = *reinterpret_cast<const float4*>(up + k0);
    float4 u1 = *reinterpret_cast<const float4*>(up + k0 + 4);
    st8(&Xs[sr][sc],      a0, a1);
    st8(&Xs[sr + 64][sc], b0, b1);
    st8(&Gs[sr][sc],      g0, g1);
    st8(&Us[sr][sc],      u0, u1);
    __syncthreads();

    bf16x8 bg0 = ldb(&Gs[wn * 32 + fr][kg * 8]);
    bf16x8 bg1 = ldb(&Gs[wn * 32 + 16 + fr][kg * 8]);
    bf16x8 bu0 = ldb(&Us[wn * 32 + fr][kg * 8]);
    bf16x8 bu1 = ldb(&Us[wn * 32 + 16 + fr][kg * 8]);
#pragma unroll
    for (int mf = 0; mf < 4; ++mf) {
      bf16x8 a = ldb(&Xs[wm * 64 + mf * 16 + fr][kg * 8]);
      accg[mf][0] = mfma16(a, bg0, accg[mf][0]);
      accg[mf][1] = mfma16(a, bg1, accg[mf][1]);
      accu[mf][0] = mfma16(a, bu0, accu[mf][0]);
      accu[mf][1] = mfma16(a, bu1, accu[mf][1]);
    }
    __syncthreads();
  }

  const size_t slot0 = (size_t)offsets[e];
  const int nbase = nt * BN + wn * 32;
#pragma unroll
  for (int mf = 0; mf < 4; ++mf) {
#pragma unroll
    for (int r = 0; r < 4; ++r) {
      int ml = wm * 64 + mf * 16 + kg * 4 + r;   // D row = (lane>>4)*4 + reg
      int m  = mt * BM + ml;
      if (m < count) {
        size_t rowoff = (slot0 + m) * (size_t)HIDDEN + nbase;
#pragma unroll
        for (int nf = 0; nf < 2; ++nf) {
          float g  = accg[mf][nf][r];
          float uu = accu[mf][nf][r];
          float hv = g / (1.f + __expf(-g)) * uu;
          h[rowoff + nf * 16 + fr] = cvt_bf16(hv);
        }
      }
    }
  }
}

// ---------------- stage 2: out += w * (h Wdown^T), grouped, bf16 MFMA ----------------
__global__ __launch_bounds__(256) void stage2_kernel(
    const ushort_t* __restrict__ h, const float* __restrict__ Wdown,
    const int* __restrict__ counts, const int* __restrict__ offsets,
    const int* __restrict__ token_list, const float* __restrict__ weight_list,
    float* __restrict__ out) {
  const int e  = blockIdx.z;
  const int mt = blockIdx.y;
  const int nt = blockIdx.x;
  const int count = counts[e];
  if (mt * BM >= count) return;

  __shared__ __align__(16) ushort_t As[BM][LDP];
  __shared__ __align__(16) ushort_t Ds[BN][LDP];
  __shared__ int   toks[BM];
  __shared__ float wts[BM];

  const int t = threadIdx.x;
  if (t < BM) {
    int m  = mt * BM + t;
    int mc = m < count ? m : count - 1;
    toks[t] = token_list[e * CAP + mc];
    wts[t]  = weight_list[e * CAP + mc];
  }
  __syncthreads();

  const float* Wd = Wdown + (size_t)e * DIM * HIDDEN + (size_t)(nt * BN) * HIDDEN;
  const int slot0b = offsets[e] + mt * BM;

  const int wid  = t >> 6;
  const int lane = t & 63;
  const int wm   = wid & 1;
  const int wn   = wid >> 1;
  const int fr   = lane & 15;
  const int kg   = lane >> 4;

  f32x4 acc[4][2];
#pragma unroll
  for (int i = 0; i < 4; ++i)
#pragma unroll
    for (int j = 0; j < 2; ++j) acc[i][j] = (f32x4)0.f;

  const int sr = t >> 2;
  const int sc = (t & 3) * 8;

  int r0 = slot0b + sr;       r0 = r0 < NROWS ? r0 : NROWS - 1;
  int r1 = slot0b + sr + 64;  r1 = r1 < NROWS ? r1 : NROWS - 1;
  const ushort_t* hp0 = h + (size_t)r0 * HIDDEN + sc;
  const ushort_t* hp1 = h + (size_t)r1 * HIDDEN + sc;
  const float*    dp  = Wd + (size_t)sr * HIDDEN + sc;

  for (int k0 = 0; k0 < HIDDEN; k0 += BK) {
    s16x8 ha = *reinterpret_cast<const s16x8*>(hp0 + k0);
    s16x8 hb = *reinterpret_cast<const s16x8*>(hp1 + k0);
    float4 d0 = *reinterpret_cast<const float4*>(dp + k0);
    float4 d1 = *reinterpret_cast<const float4*>(dp + k0 + 4);
    *reinterpret_cast<s16x8*>(&As[sr][sc])      = ha;
    *reinterpret_cast<s16x8*>(&As[sr + 64][sc]) = hb;
    st8(&Ds[sr][sc], d0, d1);
    __syncthreads();

    bf16x8 b0 = ldb(&Ds[wn * 32 + fr][kg * 8]);
    bf16x8 b1 = ldb(&Ds[wn * 32 + 16 + fr][kg * 8]);
#pragma unroll
    for (int mf = 0; mf < 4; ++mf) {
      bf16x8 a = ldb(&As[wm * 64 + mf * 16 + fr][kg * 8]);
      acc[mf][0] = mfma16(a, b0, acc[mf][0]);
      acc[mf][1] = mfma16(a, b1, acc[mf][1]);
    }
    __syncthreads();
  }

  const int nbase = nt * BN + wn * 32;
#pragma unroll
  for (int mf = 0; mf < 4; ++mf) {
#pragma unroll
    for (int r = 0; r < 4; ++r) {
      int ml = wm * 64 + mf * 16 + kg * 4 + r;
      int m  = mt * BM + ml;
      if (m < count) {
        int   tok = toks[ml];
        float w   = wts[ml];
        size_t o  = (size_t)tok * DIM + nbase;
#pragma unroll
        for (int nf = 0; nf < 2; ++nf) {
          atomicAdd(&out[o + nf * 16 + fr], acc[mf][nf][r] * w);
        }
      }
    }
  }
}

// ---------------- launch ----------------
extern "C" void kernel_launch(void* const* d_in, const int* in_sizes, int n_in,
                              void* d_out, int out_size, void* d_ws, size_t ws_size,
                              hipStream_t stream) {
  const float* x     = (const float*)d_in[0];
  const float* wg    = (const float*)d_in[1];
  const float* bg    = (const float*)d_in[2];
  const float* Wgate = (const float*)d_in[3];
  const float* Wup   = (const float*)d_in[4];
  const float* Wdown = (const float*)d_in[5];
  float* out = (float*)d_out;

  char* ws = (char*)d_ws;
  int*      counts      = (int*)(ws + WS_COUNTS);
  int*      offsets     = (int*)(ws + WS_OFFSETS);
  int*      token_list  = (int*)(ws + WS_TOKENS);
  float*    weight_list = (float*)(ws + WS_WEIGHTS);
  ushort_t* h           = (ushort_t*)(ws + WS_H);

  hipMemsetAsync(counts, 0, NE * sizeof(int), stream);
  hipMemsetAsync(out, 0, (size_t)NTOK * DIM * sizeof(float), stream);

  gating_kernel<<<NTOK / 4, 256, 0, stream>>>(x, wg, bg, counts, token_list, weight_list);
  prefix_kernel<<<1, 64, 0, stream>>>(counts, offsets);
  stage1_kernel<<<dim3(HIDDEN / BN, CAP / BM, NE), 256, 0, stream>>>(
      x, Wgate, Wup, counts, offsets, token_list, h);
  stage2_kernel<<<dim3(DIM / BN, CAP / BM, NE), 256, 0, stream>>>(
      h, Wdown, counts, offsets, token_list, weight_list, out);
}

// Round 6
// 1245.510 us; speedup vs baseline: 1.1095x; 1.1095x over previous
//
#include <hip/hip_runtime.h>
#include <cstdint>
#include <cstddef>

typedef unsigned short ushort_t;
typedef __attribute__((ext_vector_type(8))) __bf16 bf16x8;
typedef __attribute__((ext_vector_type(8))) short  s16x8;
typedef __attribute__((ext_vector_type(4))) float  f32x4;

#define NE 8
#define DIM 1024
#define HIDDEN 4096
#define NTOK 8192
#define CAP NTOK              // max rows per expert
#define NROWS (NTOK * 2)      // total routed rows = 16384

#define BM 128
#define BN 64
#define BK 32
#define LDP 40                // fallback-path padded LDS row (bf16 elems)

// ---------------- workspace layout (bytes) ----------------
static constexpr size_t WS_COUNTS  = 0;
static constexpr size_t WS_OFFSETS = 256;
static constexpr size_t WS_TOKENS  = 512;
static constexpr size_t WS_WEIGHTS = WS_TOKENS + (size_t)NE * CAP * 4;
static constexpr size_t WS_H       = ((WS_WEIGHTS + (size_t)NE * CAP * 4 + 1023) / 1024) * 1024;
static constexpr size_t H_BYTES    = (size_t)NROWS * HIDDEN * 2;
static constexpr size_t WS_XB      = WS_H + H_BYTES;
static constexpr size_t XB_BYTES   = (size_t)NTOK * DIM * 2;
static constexpr size_t W_BYTES    = (size_t)NE * HIDDEN * DIM * 2;   // 67.1 MB each
static constexpr size_t WS_WGB     = WS_XB + XB_BYTES;
static constexpr size_t WS_WUB     = WS_WGB + W_BYTES;
static constexpr size_t WS_WDB     = WS_WUB + W_BYTES;
static constexpr size_t WS_T1_END  = WS_WDB;                          // ~286 MB
static constexpr size_t WS_T2_END  = WS_WDB + W_BYTES;                // ~353 MB

// ---------------- helpers ----------------
__device__ __forceinline__ ushort_t cvt_bf16(float f) {
  unsigned u = __float_as_uint(f);
  return (ushort_t)((u + 0x7FFFu + ((u >> 16) & 1u)) >> 16);
}

__device__ __forceinline__ void st8(ushort_t* dst, float4 a, float4 b) {
  s16x8 v;
  v[0] = (short)cvt_bf16(a.x); v[1] = (short)cvt_bf16(a.y);
  v[2] = (short)cvt_bf16(a.z); v[3] = (short)cvt_bf16(a.w);
  v[4] = (short)cvt_bf16(b.x); v[5] = (short)cvt_bf16(b.y);
  v[6] = (short)cvt_bf16(b.z); v[7] = (short)cvt_bf16(b.w);
  *reinterpret_cast<s16x8*>(dst) = v;
}

__device__ __forceinline__ bf16x8 ldb(const ushort_t* p) {
  union { s16x8 s; bf16x8 b; } u;
  u.s = *reinterpret_cast<const s16x8*>(p);
  return u.b;
}

// swizzled LDS tile: rows of 32 bf16 (4 x 16B slots); slot map s' = s ^ ((row>>1)&3)
__device__ __forceinline__ bf16x8 ldt(const ushort_t* base, int row, int s) {
  return ldb(base + (size_t)((row << 2) + (s ^ ((row >> 1) & 3))) * 8);
}

__device__ __forceinline__ f32x4 mfma16(bf16x8 a, bf16x8 b, f32x4 c) {
  return __builtin_amdgcn_mfma_f32_16x16x32_bf16(a, b, c, 0, 0, 0);
}

#define GLDS16(g, l)                                                     \
  __builtin_amdgcn_global_load_lds(                                      \
      (const __attribute__((address_space(1))) unsigned int*)(g),        \
      (__attribute__((address_space(3))) unsigned int*)(l), 16, 0, 0)

// ---------------- fp32 -> bf16 bulk convert ----------------
__global__ __launch_bounds__(256) void cvt_kernel(const float* __restrict__ s,
                                                  ushort_t* __restrict__ d, long n8) {
  long i = (long)blockIdx.x * 256 + threadIdx.x;
  long stride = (long)gridDim.x * 256;
  for (long p = i; p < n8; p += stride) {
    const float4* sp = reinterpret_cast<const float4*>(s) + 2 * p;
    float4 a = sp[0];
    float4 b = sp[1];
    st8(d + p * 8, a, b);
  }
}

// ---------------- gating: wave per token ----------------
__global__ __launch_bounds__(256) void gating_kernel(
    const float* __restrict__ x, const float* __restrict__ wg,
    const float* __restrict__ bg, int* __restrict__ counts,
    int* __restrict__ token_list, float* __restrict__ weight_list) {
  int gid  = blockIdx.x * blockDim.x + threadIdx.x;
  int tok  = gid >> 6;
  int lane = threadIdx.x & 63;
  if (tok >= NTOK) return;
  const float* xr = x + (size_t)tok * DIM;

  float part[NE];
#pragma unroll
  for (int e = 0; e < NE; ++e) part[e] = 0.f;
  for (int i = lane; i < DIM; i += 64) {
    float xv = xr[i];
#pragma unroll
    for (int e = 0; e < NE; ++e) part[e] = fmaf(xv, wg[e * DIM + i], part[e]);
  }
#pragma unroll
  for (int e = 0; e < NE; ++e) {
    float v = part[e];
#pragma unroll
    for (int o = 32; o > 0; o >>= 1) v += __shfl_xor(v, o, 64);
    part[e] = v + bg[e];
  }
  if (lane == 0) {
    int i0 = 0; float v0 = part[0];
#pragma unroll
    for (int e = 1; e < NE; ++e) if (part[e] > v0) { v0 = part[e]; i0 = e; }
    int i1 = -1; float v1 = -INFINITY;
#pragma unroll
    for (int e = 0; e < NE; ++e) if (e != i0 && part[e] > v1) { v1 = part[e]; i1 = e; }
    float e1 = expf(v1 - v0);
    float s  = 1.f + e1;
    float w0 = 1.f / s;
    float w1 = e1 / s;
    int s0 = atomicAdd(&counts[i0], 1);
    token_list[i0 * CAP + s0]  = tok;
    weight_list[i0 * CAP + s0] = w0;
    int s1 = atomicAdd(&counts[i1], 1);
    token_list[i1 * CAP + s1]  = tok;
    weight_list[i1 * CAP + s1] = w1;
  }
}

__global__ void prefix_kernel(const int* __restrict__ counts, int* __restrict__ offsets) {
  if (threadIdx.x == 0) {
    int acc = 0;
    for (int e = 0; e < NE; ++e) { offsets[e] = acc; acc += counts[e]; }
  }
}

// ---------------- stage 1 (bf16 weights, global_load_lds, swizzled LDS) ----------------
__global__ __launch_bounds__(256) void stage1_kernel(
    const ushort_t* __restrict__ xb, const ushort_t* __restrict__ wgb,
    const ushort_t* __restrict__ wub, const int* __restrict__ counts,
    const int* __restrict__ offsets, const int* __restrict__ token_list,
    ushort_t* __restrict__ h) {
  const int e  = blockIdx.z;
  const int mt = blockIdx.y;
  const int nt = blockIdx.x;
  const int count = counts[e];
  if (mt * BM >= count) return;

  __shared__ __align__(16) ushort_t XsL[BM * 32];
  __shared__ __align__(16) ushort_t GsL[BN * 32];
  __shared__ __align__(16) ushort_t UsL[BN * 32];
  __shared__ int toks[BM];

  const int t = threadIdx.x;
  if (t < BM) {
    int m = mt * BM + t;
    toks[t] = token_list[e * CAP + (m < count ? m : count - 1)];
  }
  __syncthreads();

  const int wid  = t >> 6;
  const int lane = t & 63;
  const int wm   = wid & 1;
  const int wn   = wid >> 1;
  const int fr   = lane & 15;
  const int kg   = lane >> 4;

  // per-lane pre-swizzled global sources (hoisted; advance by k0 each iter)
  const int uA = wid * 128 + lane;            // Xs call A: units [wid*128, +64)
  const int uB = uA + 64;                     // Xs call B
  const int rA = uA >> 2, sA = (uA & 3) ^ ((rA >> 1) & 3);
  const int rB = uB >> 2, sB = (uB & 3) ^ ((rB >> 1) & 3);
  const ushort_t* gxA = xb + (size_t)toks[rA] * DIM + sA * 8;
  const ushort_t* gxB = xb + (size_t)toks[rB] * DIM + sB * 8;

  const int uG = wid * 64 + lane;             // Gs/Us: units [wid*64, +64)
  const int rG = uG >> 2, sG = (uG & 3) ^ ((rG >> 1) & 3);
  const size_t wrow = (size_t)e * HIDDEN + (size_t)nt * BN + rG;
  const ushort_t* ggp = wgb + wrow * DIM + sG * 8;
  const ushort_t* gup = wub + wrow * DIM + sG * 8;

  ushort_t* ldsXA = XsL + (size_t)(wid * 128) * 8;   // uniform per wave
  ushort_t* ldsXB = XsL + (size_t)(wid * 128 + 64) * 8;
  ushort_t* ldsG  = GsL + (size_t)(wid * 64) * 8;
  ushort_t* ldsU  = UsL + (size_t)(wid * 64) * 8;

  f32x4 accg[4][2], accu[4][2];
#pragma unroll
  for (int i = 0; i < 4; ++i)
#pragma unroll
    for (int j = 0; j < 2; ++j) { accg[i][j] = (f32x4)0.f; accu[i][j] = (f32x4)0.f; }

  for (int k0 = 0; k0 < DIM; k0 += BK) {
    GLDS16(gxA + k0, ldsXA);
    GLDS16(gxB + k0, ldsXB);
    GLDS16(ggp + k0, ldsG);
    GLDS16(gup + k0, ldsU);
    __syncthreads();

    bf16x8 bg0 = ldt(GsL, wn * 32 + fr, kg);
    bf16x8 bg1 = ldt(GsL, wn * 32 + 16 + fr, kg);
    bf16x8 bu0 = ldt(UsL, wn * 32 + fr, kg);
    bf16x8 bu1 = ldt(UsL, wn * 32 + 16 + fr, kg);
#pragma unroll
    for (int mf = 0; mf < 4; ++mf) {
      bf16x8 a = ldt(XsL, wm * 64 + mf * 16 + fr, kg);
      accg[mf][0] = mfma16(a, bg0, accg[mf][0]);
      accg[mf][1] = mfma16(a, bg1, accg[mf][1]);
      accu[mf][0] = mfma16(a, bu0, accu[mf][0]);
      accu[mf][1] = mfma16(a, bu1, accu[mf][1]);
    }
    __syncthreads();
  }

  const size_t slot0 = (size_t)offsets[e];
  const int nbase = nt * BN + wn * 32;
#pragma unroll
  for (int mf = 0; mf < 4; ++mf) {
#pragma unroll
    for (int r = 0; r < 4; ++r) {
      int ml = wm * 64 + mf * 16 + kg * 4 + r;
      int m  = mt * BM + ml;
      if (m < count) {
        size_t rowoff = (slot0 + m) * (size_t)HIDDEN + nbase;
#pragma unroll
        for (int nf = 0; nf < 2; ++nf) {
          float g  = accg[mf][nf][r];
          float uu = accu[mf][nf][r];
          float hv = g / (1.f + __expf(-g)) * uu;
          h[rowoff + nf * 16 + fr] = cvt_bf16(hv);
        }
      }
    }
  }
}

// ---------------- stage 2 (bf16 weights, global_load_lds, swizzled LDS) ----------------
__global__ __launch_bounds__(256) void stage2_kernel(
    const ushort_t* __restrict__ h, const ushort_t* __restrict__ wdb,
    const int* __restrict__ counts, const int* __restrict__ offsets,
    const int* __restrict__ token_list, const float* __restrict__ weight_list,
    float* __restrict__ out) {
  const int e  = blockIdx.z;
  const int mt = blockIdx.y;
  const int nt = blockIdx.x;
  const int count = counts[e];
  if (mt * BM >= count) return;

  __shared__ __align__(16) ushort_t AsL[BM * 32];
  __shared__ __align__(16) ushort_t DsL[BN * 32];
  __shared__ int   toks[BM];
  __shared__ float wts[BM];

  const int t = threadIdx.x;
  if (t < BM) {
    int m  = mt * BM + t;
    int mc = m < count ? m : count - 1;
    toks[t] = token_list[e * CAP + mc];
    wts[t]  = weight_list[e * CAP + mc];
  }
  __syncthreads();

  const int wid  = t >> 6;
  const int lane = t & 63;
  const int wm   = wid & 1;
  const int wn   = wid >> 1;
  const int fr   = lane & 15;
  const int kg   = lane >> 4;

  const int slot0b = offsets[e] + mt * BM;

  const int uA = wid * 128 + lane;
  const int uB = uA + 64;
  const int rA = uA >> 2, sA = (uA & 3) ^ ((rA >> 1) & 3);
  const int rB = uB >> 2, sB = (uB & 3) ^ ((rB >> 1) & 3);
  int hrA = slot0b + rA; hrA = hrA < NROWS ? hrA : NROWS - 1;
  int hrB = slot0b + rB; hrB = hrB < NROWS ? hrB : NROWS - 1;
  const ushort_t* ghA = h + (size_t)hrA * HIDDEN + sA * 8;
  const ushort_t* ghB = h + (size_t)hrB * HIDDEN + sB * 8;

  const int uD = wid * 64 + lane;
  const int rD = uD >> 2, sD = (uD & 3) ^ ((rD >> 1) & 3);
  const ushort_t* gdp = wdb + ((size_t)e * DIM + (size_t)nt * BN + rD) * HIDDEN + sD * 8;

  ushort_t* ldsAA = AsL + (size_t)(wid * 128) * 8;
  ushort_t* ldsAB = AsL + (size_t)(wid * 128 + 64) * 8;
  ushort_t* ldsD  = DsL + (size_t)(wid * 64) * 8;

  f32x4 acc[4][2];
#pragma unroll
  for (int i = 0; i < 4; ++i)
#pragma unroll
    for (int j = 0; j < 2; ++j) acc[i][j] = (f32x4)0.f;

  for (int k0 = 0; k0 < HIDDEN; k0 += BK) {
    GLDS16(ghA + k0, ldsAA);
    GLDS16(ghB + k0, ldsAB);
    GLDS16(gdp + k0, ldsD);
    __syncthreads();

    bf16x8 b0 = ldt(DsL, wn * 32 + fr, kg);
    bf16x8 b1 = ldt(DsL, wn * 32 + 16 + fr, kg);
#pragma unroll
    for (int mf = 0; mf < 4; ++mf) {
      bf16x8 a = ldt(AsL, wm * 64 + mf * 16 + fr, kg);
      acc[mf][0] = mfma16(a, b0, acc[mf][0]);
      acc[mf][1] = mfma16(a, b1, acc[mf][1]);
    }
    __syncthreads();
  }

  const int nbase = nt * BN + wn * 32;
#pragma unroll
  for (int mf = 0; mf < 4; ++mf) {
#pragma unroll
    for (int r = 0; r < 4; ++r) {
      int ml = wm * 64 + mf * 16 + kg * 4 + r;
      int m  = mt * BM + ml;
      if (m < count) {
        int   tok = toks[ml];
        float w   = wts[ml];
        size_t o  = (size_t)tok * DIM + nbase;
#pragma unroll
        for (int nf = 0; nf < 2; ++nf) {
          atomicAdd(&out[o + nf * 16 + fr], acc[mf][nf][r] * w);
        }
      }
    }
  }
}

// ================= fallback path (fp32 weights in-loop, validated in R2) =================
__global__ __launch_bounds__(256) void stage1_f32w(
    const float* __restrict__ x, const float* __restrict__ Wgate,
    const float* __restrict__ Wup, const int* __restrict__ counts,
    const int* __restrict__ offsets, const int* __restrict__ token_list,
    ushort_t* __restrict__ h) {
  const int e  = blockIdx.z;
  const int mt = blockIdx.y;
  const int nt = blockIdx.x;
  const int count = counts[e];
  if (mt * BM >= count) return;

  __shared__ __align__(16) ushort_t Xs[BM][LDP];
  __shared__ __align__(16) ushort_t Gs[BN][LDP];
  __shared__ __align__(16) ushort_t Us[BN][LDP];
  __shared__ int toks[BM];

  const int t = threadIdx.x;
  if (t < BM) {
    int m = mt * BM + t;
    toks[t] = token_list[e * CAP + (m < count ? m : count - 1)];
  }
  __syncthreads();

  const float* Wg = Wgate + (size_t)e * HIDDEN * DIM + (size_t)(nt * BN) * DIM;
  const float* Wu = Wup   + (size_t)e * HIDDEN * DIM + (size_t)(nt * BN) * DIM;

  const int wid  = t >> 6;
  const int lane = t & 63;
  const int wm   = wid & 1;
  const int wn   = wid >> 1;
  const int fr   = lane & 15;
  const int kg   = lane >> 4;

  f32x4 accg[4][2], accu[4][2];
#pragma unroll
  for (int i = 0; i < 4; ++i)
#pragma unroll
    for (int j = 0; j < 2; ++j) { accg[i][j] = (f32x4)0.f; accu[i][j] = (f32x4)0.f; }

  const int sr = t >> 2;
  const int sc = (t & 3) * 8;

  const int tok0 = toks[sr];
  const int tok1 = toks[sr + 64];
  const float* xp0 = x + (size_t)tok0 * DIM + sc;
  const float* xp1 = x + (size_t)tok1 * DIM + sc;
  const float* gp  = Wg + (size_t)sr * DIM + sc;
  const float* up  = Wu + (size_t)sr * DIM + sc;

  for (int k0 = 0; k0 < DIM; k0 += BK) {
    float4 a0 = *reinterpret_cast<const float4*>(xp0 + k0);
    float4 a1 = *reinterpret_cast<const float4*>(xp0 + k0 + 4);
    float4 b0 = *reinterpret_cast<const float4*>(xp1 + k0);
    float4 b1 = *reinterpret_cast<const float4*>(xp1 + k0 + 4);
    float4 g0 = *reinterpret_cast<const float4*>(gp + k0);
    float4 g1 = *reinterpret_cast<const float4*>(gp + k0 + 4);
    float4 u0 = *reinterpret_cast<const float4*>(up + k0);
    float4 u1 = *reinterpret_cast<const float4*>(up + k0 + 4);
    st8(&Xs[sr][sc],      a0, a1);
    st8(&Xs[sr + 64][sc], b0, b1);
    st8(&Gs[sr][sc],      g0, g1);
    st8(&Us[sr][sc],      u0, u1);
    __syncthreads();

    bf16x8 bg0 = ldb(&Gs[wn * 32 + fr][kg * 8]);
    bf16x8 bg1 = ldb(&Gs[wn * 32 + 16 + fr][kg * 8]);
    bf16x8 bu0 = ldb(&Us[wn * 32 + fr][kg * 8]);
    bf16x8 bu1 = ldb(&Us[wn * 32 + 16 + fr][kg * 8]);
#pragma unroll
    for (int mf = 0; mf < 4; ++mf) {
      bf16x8 a = ldb(&Xs[wm * 64 + mf * 16 + fr][kg * 8]);
      accg[mf][0] = mfma16(a, bg0, accg[mf][0]);
      accg[mf][1] = mfma16(a, bg1, accg[mf][1]);
      accu[mf][0] = mfma16(a, bu0, accu[mf][0]);
      accu[mf][1] = mfma16(a, bu1, accu[mf][1]);
    }
    __syncthreads();
  }

  const size_t slot0 = (size_t)offsets[e];
  const int nbase = nt * BN + wn * 32;
#pragma unroll
  for (int mf = 0; mf < 4; ++mf) {
#pragma unroll
    for (int r = 0; r < 4; ++r) {
      int ml = wm * 64 + mf * 16 + kg * 4 + r;
      int m  = mt * BM + ml;
      if (m < count) {
        size_t rowoff = (slot0 + m) * (size_t)HIDDEN + nbase;
#pragma unroll
        for (int nf = 0; nf < 2; ++nf) {
          float g  = accg[mf][nf][r];
          float uu = accu[mf][nf][r];
          float hv = g / (1.f + __expf(-g)) * uu;
          h[rowoff + nf * 16 + fr] = cvt_bf16(hv);
        }
      }
    }
  }
}

__global__ __launch_bounds__(256) void stage2_f32w(
    const ushort_t* __restrict__ h, const float* __restrict__ Wdown,
    const int* __restrict__ counts, const int* __restrict__ offsets,
    const int* __restrict__ token_list, const float* __restrict__ weight_list,
    float* __restrict__ out) {
  const int e  = blockIdx.z;
  const int mt = blockIdx.y;
  const int nt = blockIdx.x;
  const int count = counts[e];
  if (mt * BM >= count) return;

  __shared__ __align__(16) ushort_t As[BM][LDP];
  __shared__ __align__(16) ushort_t Ds[BN][LDP];
  __shared__ int   toks[BM];
  __shared__ float wts[BM];

  const int t = threadIdx.x;
  if (t < BM) {
    int m  = mt * BM + t;
    int mc = m < count ? m : count - 1;
    toks[t] = token_list[e * CAP + mc];
    wts[t]  = weight_list[e * CAP + mc];
  }
  __syncthreads();

  const float* Wd = Wdown + (size_t)e * DIM * HIDDEN + (size_t)(nt * BN) * HIDDEN;
  const int slot0b = offsets[e] + mt * BM;

  const int wid  = t >> 6;
  const int lane = t & 63;
  const int wm   = wid & 1;
  const int wn   = wid >> 1;
  const int fr   = lane & 15;
  const int kg   = lane >> 4;

  f32x4 acc[4][2];
#pragma unroll
  for (int i = 0; i < 4; ++i)
#pragma unroll
    for (int j = 0; j < 2; ++j) acc[i][j] = (f32x4)0.f;

  const int sr = t >> 2;
  const int sc = (t & 3) * 8;

  int r0 = slot0b + sr;       r0 = r0 < NROWS ? r0 : NROWS - 1;
  int r1 = slot0b + sr + 64;  r1 = r1 < NROWS ? r1 : NROWS - 1;
  const ushort_t* hp0 = h + (size_t)r0 * HIDDEN + sc;
  const ushort_t* hp1 = h + (size_t)r1 * HIDDEN + sc;
  const float*    dp  = Wd + (size_t)sr * HIDDEN + sc;

  for (int k0 = 0; k0 < HIDDEN; k0 += BK) {
    s16x8 ha = *reinterpret_cast<const s16x8*>(hp0 + k0);
    s16x8 hb = *reinterpret_cast<const s16x8*>(hp1 + k0);
    float4 d0 = *reinterpret_cast<const float4*>(dp + k0);
    float4 d1 = *reinterpret_cast<const float4*>(dp + k0 + 4);
    *reinterpret_cast<s16x8*>(&As[sr][sc])      = ha;
    *reinterpret_cast<s16x8*>(&As[sr + 64][sc]) = hb;
    st8(&Ds[sr][sc], d0, d1);
    __syncthreads();

    bf16x8 b0 = ldb(&Ds[wn * 32 + fr][kg * 8]);
    bf16x8 b1 = ldb(&Ds[wn * 32 + 16 + fr][kg * 8]);
#pragma unroll
    for (int mf = 0; mf < 4; ++mf) {
      bf16x8 a = ldb(&As[wm * 64 + mf * 16 + fr][kg * 8]);
      acc[mf][0] = mfma16(a, b0, acc[mf][0]);
      acc[mf][1] = mfma16(a, b1, acc[mf][1]);
    }
    __syncthreads();
  }

  const int nbase = nt * BN + wn * 32;
#pragma unroll
  for (int mf = 0; mf < 4; ++mf) {
#pragma unroll
    for (int r = 0; r < 4; ++r) {
      int ml = wm * 64 + mf * 16 + kg * 4 + r;
      int m  = mt * BM + ml;
      if (m < count) {
        int   tok = toks[ml];
        float w   = wts[ml];
        size_t o  = (size_t)tok * DIM + nbase;
#pragma unroll
        for (int nf = 0; nf < 2; ++nf) {
          atomicAdd(&out[o + nf * 16 + fr], acc[mf][nf][r] * w);
        }
      }
    }
  }
}

// ---------------- launch ----------------
extern "C" void kernel_launch(void* const* d_in, const int* in_sizes, int n_in,
                              void* d_out, int out_size, void* d_ws, size_t ws_size,
                              hipStream_t stream) {
  const float* x     = (const float*)d_in[0];
  const float* wg    = (const float*)d_in[1];
  const float* bg    = (const float*)d_in[2];
  const float* Wgate = (const float*)d_in[3];
  const float* Wup   = (const float*)d_in[4];
  const float* Wdown = (const float*)d_in[5];
  float* out = (float*)d_out;

  char* ws = (char*)d_ws;
  int*      counts      = (int*)(ws + WS_COUNTS);
  int*      offsets     = (int*)(ws + WS_OFFSETS);
  int*      token_list  = (int*)(ws + WS_TOKENS);
  float*    weight_list = (float*)(ws + WS_WEIGHTS);
  ushort_t* h           = (ushort_t*)(ws + WS_H);

  hipMemsetAsync(counts, 0, NE * sizeof(int), stream);
  hipMemsetAsync(out, 0, (size_t)NTOK * DIM * sizeof(float), stream);

  gating_kernel<<<NTOK / 4, 256, 0, stream>>>(x, wg, bg, counts, token_list, weight_list);
  prefix_kernel<<<1, 64, 0, stream>>>(counts, offsets);

  const bool tier1 = ws_size >= WS_T1_END;   // xb + wgb + wub fit
  const bool tier2 = ws_size >= WS_T2_END;   // + wdb fits

  if (tier1) {
    ushort_t* xb  = (ushort_t*)(ws + WS_XB);
    ushort_t* wgb = (ushort_t*)(ws + WS_WGB);
    ushort_t* wub = (ushort_t*)(ws + WS_WUB);

    long w8 = (long)NE * HIDDEN * DIM / 8;
    long x8 = (long)NTOK * DIM / 8;
    cvt_kernel<<<8192, 256, 0, stream>>>(Wgate, wgb, w8);
    cvt_kernel<<<8192, 256, 0, stream>>>(Wup,   wub, w8);
    cvt_kernel<<<4096, 256, 0, stream>>>(x,     xb,  x8);

    stage1_kernel<<<dim3(HIDDEN / BN, CAP / BM, NE), 256, 0, stream>>>(
        xb, wgb, wub, counts, offsets, token_list, h);

    if (tier2) {
      ushort_t* wdb = (ushort_t*)(ws + WS_WDB);
      cvt_kernel<<<8192, 256, 0, stream>>>(Wdown, wdb, w8);
      stage2_kernel<<<dim3(DIM / BN, CAP / BM, NE), 256, 0, stream>>>(
          h, wdb, counts, offsets, token_list, weight_list, out);
    } else {
      stage2_f32w<<<dim3(DIM / BN, CAP / BM, NE), 256, 0, stream>>>(
          h, Wdown, counts, offsets, token_list, weight_list, out);
    }
  } else {
    stage1_f32w<<<dim3(HIDDEN / BN, CAP / BM, NE), 256, 0, stream>>>(
        x, Wgate, Wup, counts, offsets, token_list, h);
    stage2_f32w<<<dim3(DIM / BN, CAP / BM, NE), 256, 0, stream>>>(
        h, Wdown, counts, offsets, token_list, weight_list, out);
  }
}

// Round 8
// 1221.837 us; speedup vs baseline: 1.1310x; 1.0194x over previous
//
#include <hip/hip_runtime.h>
#include <cstdint>
#include <cstddef>

typedef unsigned short ushort_t;
typedef __attribute__((ext_vector_type(8))) __bf16 bf16x8;
typedef __attribute__((ext_vector_type(8))) short  s16x8;
typedef __attribute__((ext_vector_type(4))) float  f32x4;

#define NE 8
#define DIM 1024
#define HIDDEN 4096
#define NTOK 8192
#define CAP NTOK              // max rows per expert (power of 2: pos fits in 13 bits)
#define NROWS (NTOK * 2)      // total routed rows = 16384

#define BM 128
#define BN 64
#define BK 32
#define LDP 40                // fallback-path padded LDS row (bf16 elems)

// ---------------- workspace layout (bytes) ----------------
static constexpr size_t WS_COUNTS  = 0;                                   // 8 ints
static constexpr size_t WS_OFFSETS = 256;                                 // 8 ints
static constexpr size_t WS_TPAIR   = 512;                                 // NTOK*2 ints (64 KB)
static constexpr size_t WS_TOKENS  = WS_TPAIR + (size_t)NTOK * 2 * 4;     // NE*CAP ints
static constexpr size_t WS_WEIGHTS = WS_TOKENS + (size_t)NE * CAP * 4;    // NE*CAP floats
static constexpr size_t WS_H       = ((WS_WEIGHTS + (size_t)NE * CAP * 4 + 1023) / 1024) * 1024;
static constexpr size_t H_BYTES    = (size_t)NROWS * HIDDEN * 2;          // 128 MiB
static constexpr size_t WS_XB      = WS_H + H_BYTES;
static constexpr size_t XB_BYTES   = (size_t)NTOK * DIM * 2;              // 16 MiB
static constexpr size_t W_BYTES    = (size_t)NE * HIDDEN * DIM * 2;       // 64 MiB each
static constexpr size_t WS_WA      = WS_XB + XB_BYTES;   // Wgate-bf16 during stage1, Wdown-bf16 after
static constexpr size_t WS_WUB     = WS_WA + W_BYTES;
static constexpr size_t WS_T1_END  = WS_WUB + W_BYTES;                    // ~286 MB: full bf16 path
static constexpr size_t WS_Y       = WS_T1_END;
static constexpr size_t Y_BYTES    = (size_t)NROWS * DIM * 4;             // 64 MiB fp32 rows
static constexpr size_t WS_T3_END  = WS_Y + Y_BYTES;                      // ~353 MB: no-atomic path

// ---------------- helpers ----------------
__device__ __forceinline__ ushort_t cvt_bf16(float f) {
  unsigned u = __float_as_uint(f);
  return (ushort_t)((u + 0x7FFFu + ((u >> 16) & 1u)) >> 16);
}

__device__ __forceinline__ void st8(ushort_t* dst, float4 a, float4 b) {
  s16x8 v;
  v[0] = (short)cvt_bf16(a.x); v[1] = (short)cvt_bf16(a.y);
  v[2] = (short)cvt_bf16(a.z); v[3] = (short)cvt_bf16(a.w);
  v[4] = (short)cvt_bf16(b.x); v[5] = (short)cvt_bf16(b.y);
  v[6] = (short)cvt_bf16(b.z); v[7] = (short)cvt_bf16(b.w);
  *reinterpret_cast<s16x8*>(dst) = v;
}

__device__ __forceinline__ bf16x8 ldb(const ushort_t* p) {
  union { s16x8 s; bf16x8 b; } u;
  u.s = *reinterpret_cast<const s16x8*>(p);
  return u.b;
}

// swizzled LDS tile: rows of 32 bf16 (4 x 16B slots); slot map s' = s ^ ((row>>1)&3)
__device__ __forceinline__ bf16x8 ldt(const ushort_t* base, int row, int s) {
  return ldb(base + (size_t)((row << 2) + (s ^ ((row >> 1) & 3))) * 8);
}

__device__ __forceinline__ f32x4 mfma16(bf16x8 a, bf16x8 b, f32x4 c) {
  return __builtin_amdgcn_mfma_f32_16x16x32_bf16(a, b, c, 0, 0, 0);
}

#define GLDS16(g, l)                                                     \
  __builtin_amdgcn_global_load_lds(                                      \
      (const __attribute__((address_space(1))) unsigned int*)(g),        \
      (__attribute__((address_space(3))) unsigned int*)(l), 16, 0, 0)

// ---------------- fp32 -> bf16 bulk convert ----------------
__global__ __launch_bounds__(256) void cvt_kernel(const float* __restrict__ s,
                                                  ushort_t* __restrict__ d, long n8) {
  long i = (long)blockIdx.x * 256 + threadIdx.x;
  long stride = (long)gridDim.x * 256;
  for (long p = i; p < n8; p += stride) {
    const float4* sp = reinterpret_cast<const float4*>(s) + 2 * p;
    float4 a = sp[0];
    float4 b = sp[1];
    st8(d + p * 8, a, b);
  }
}

// ---------------- gating: wave per token ----------------
__global__ __launch_bounds__(256) void gating_kernel(
    const float* __restrict__ x, const float* __restrict__ wg,
    const float* __restrict__ bg, int* __restrict__ counts,
    int* __restrict__ token_list, float* __restrict__ weight_list,
    int* __restrict__ tpair) {
  int gid  = blockIdx.x * blockDim.x + threadIdx.x;
  int tok  = gid >> 6;
  int lane = threadIdx.x & 63;
  if (tok >= NTOK) return;
  const float* xr = x + (size_t)tok * DIM;

  float part[NE];
#pragma unroll
  for (int e = 0; e < NE; ++e) part[e] = 0.f;
  for (int i = lane; i < DIM; i += 64) {
    float xv = xr[i];
#pragma unroll
    for (int e = 0; e < NE; ++e) part[e] = fmaf(xv, wg[e * DIM + i], part[e]);
  }
#pragma unroll
  for (int e = 0; e < NE; ++e) {
    float v = part[e];
#pragma unroll
    for (int o = 32; o > 0; o >>= 1) v += __shfl_xor(v, o, 64);
    part[e] = v + bg[e];
  }
  if (lane == 0) {
    int i0 = 0; float v0 = part[0];
#pragma unroll
    for (int e = 1; e < NE; ++e) if (part[e] > v0) { v0 = part[e]; i0 = e; }
    int i1 = -1; float v1 = -INFINITY;
#pragma unroll
    for (int e = 0; e < NE; ++e) if (e != i0 && part[e] > v1) { v1 = part[e]; i1 = e; }
    float e1 = expf(v1 - v0);
    float s  = 1.f + e1;
    float w0 = 1.f / s;
    float w1 = e1 / s;
    int s0 = atomicAdd(&counts[i0], 1);
    token_list[i0 * CAP + s0]  = tok;
    weight_list[i0 * CAP + s0] = w0;
    tpair[tok * 2 + 0] = i0 * CAP + s0;
    int s1 = atomicAdd(&counts[i1], 1);
    token_list[i1 * CAP + s1]  = tok;
    weight_list[i1 * CAP + s1] = w1;
    tpair[tok * 2 + 1] = i1 * CAP + s1;
  }
}

__global__ void prefix_kernel(const int* __restrict__ counts, int* __restrict__ offsets) {
  if (threadIdx.x == 0) {
    int acc = 0;
    for (int e = 0; e < NE; ++e) { offsets[e] = acc; acc += counts[e]; }
  }
}

// ---------------- stage 1 (bf16 weights, global_load_lds, swizzled LDS) ----------------
__global__ __launch_bounds__(256) void stage1_kernel(
    const ushort_t* __restrict__ xb, const ushort_t* __restrict__ wgb,
    const ushort_t* __restrict__ wub, const int* __restrict__ counts,
    const int* __restrict__ offsets, const int* __restrict__ token_list,
    ushort_t* __restrict__ h) {
  const int e  = blockIdx.z;
  const int mt = blockIdx.y;
  const int nt = blockIdx.x;
  const int count = counts[e];
  if (mt * BM >= count) return;

  __shared__ __align__(16) ushort_t XsL[BM * 32];
  __shared__ __align__(16) ushort_t GsL[BN * 32];
  __shared__ __align__(16) ushort_t UsL[BN * 32];
  __shared__ int toks[BM];

  const int t = threadIdx.x;
  if (t < BM) {
    int m = mt * BM + t;
    toks[t] = token_list[e * CAP + (m < count ? m : count - 1)];
  }
  __syncthreads();

  const int wid  = t >> 6;
  const int lane = t & 63;
  const int wm   = wid & 1;
  const int wn   = wid >> 1;
  const int fr   = lane & 15;
  const int kg   = lane >> 4;

  const int uA = wid * 128 + lane;
  const int uB = uA + 64;
  const int rA = uA >> 2, sA = (uA & 3) ^ ((rA >> 1) & 3);
  const int rB = uB >> 2, sB = (uB & 3) ^ ((rB >> 1) & 3);
  const ushort_t* gxA = xb + (size_t)toks[rA] * DIM + sA * 8;
  const ushort_t* gxB = xb + (size_t)toks[rB] * DIM + sB * 8;

  const int uG = wid * 64 + lane;
  const int rG = uG >> 2, sG = (uG & 3) ^ ((rG >> 1) & 3);
  const size_t wrow = (size_t)e * HIDDEN + (size_t)nt * BN + rG;
  const ushort_t* ggp = wgb + wrow * DIM + sG * 8;
  const ushort_t* gup = wub + wrow * DIM + sG * 8;

  ushort_t* ldsXA = XsL + (size_t)(wid * 128) * 8;
  ushort_t* ldsXB = XsL + (size_t)(wid * 128 + 64) * 8;
  ushort_t* ldsG  = GsL + (size_t)(wid * 64) * 8;
  ushort_t* ldsU  = UsL + (size_t)(wid * 64) * 8;

  f32x4 accg[4][2], accu[4][2];
#pragma unroll
  for (int i = 0; i < 4; ++i)
#pragma unroll
    for (int j = 0; j < 2; ++j) { accg[i][j] = (f32x4)0.f; accu[i][j] = (f32x4)0.f; }

  for (int k0 = 0; k0 < DIM; k0 += BK) {
    GLDS16(gxA + k0, ldsXA);
    GLDS16(gxB + k0, ldsXB);
    GLDS16(ggp + k0, ldsG);
    GLDS16(gup + k0, ldsU);
    __syncthreads();

    bf16x8 bg0 = ldt(GsL, wn * 32 + fr, kg);
    bf16x8 bg1 = ldt(GsL, wn * 32 + 16 + fr, kg);
    bf16x8 bu0 = ldt(UsL, wn * 32 + fr, kg);
    bf16x8 bu1 = ldt(UsL, wn * 32 + 16 + fr, kg);
#pragma unroll
    for (int mf = 0; mf < 4; ++mf) {
      bf16x8 a = ldt(XsL, wm * 64 + mf * 16 + fr, kg);
      accg[mf][0] = mfma16(a, bg0, accg[mf][0]);
      accg[mf][1] = mfma16(a, bg1, accg[mf][1]);
      accu[mf][0] = mfma16(a, bu0, accu[mf][0]);
      accu[mf][1] = mfma16(a, bu1, accu[mf][1]);
    }
    __syncthreads();
  }

  const size_t slot0 = (size_t)offsets[e];
  const int nbase = nt * BN + wn * 32;
#pragma unroll
  for (int mf = 0; mf < 4; ++mf) {
#pragma unroll
    for (int r = 0; r < 4; ++r) {
      int ml = wm * 64 + mf * 16 + kg * 4 + r;
      int m  = mt * BM + ml;
      if (m < count) {
        size_t rowoff = (slot0 + m) * (size_t)HIDDEN + nbase;
#pragma unroll
        for (int nf = 0; nf < 2; ++nf) {
          float g  = accg[mf][nf][r];
          float uu = accu[mf][nf][r];
          float hv = g / (1.f + __expf(-g)) * uu;
          h[rowoff + nf * 16 + fr] = cvt_bf16(hv);
        }
      }
    }
  }
}

// ---------------- stage 2 core loop (bf16 h + bf16 Wdown, swizzled LDS) ----------------
// TIER3 variant: plain stores of unweighted rows into y (no atomics).
__global__ __launch_bounds__(256) void stage2_y_kernel(
    const ushort_t* __restrict__ h, const ushort_t* __restrict__ wdb,
    const int* __restrict__ counts, const int* __restrict__ offsets,
    float* __restrict__ y) {
  const int e  = blockIdx.z;
  const int mt = blockIdx.y;
  const int nt = blockIdx.x;
  const int count = counts[e];
  if (mt * BM >= count) return;

  __shared__ __align__(16) ushort_t AsL[BM * 32];
  __shared__ __align__(16) ushort_t DsL[BN * 32];

  const int t = threadIdx.x;
  const int wid  = t >> 6;
  const int lane = t & 63;
  const int wm   = wid & 1;
  const int wn   = wid >> 1;
  const int fr   = lane & 15;
  const int kg   = lane >> 4;

  const int slot0b = offsets[e] + mt * BM;

  const int uA = wid * 128 + lane;
  const int uB = uA + 64;
  const int rA = uA >> 2, sA = (uA & 3) ^ ((rA >> 1) & 3);
  const int rB = uB >> 2, sB = (uB & 3) ^ ((rB >> 1) & 3);
  int hrA = slot0b + rA; hrA = hrA < NROWS ? hrA : NROWS - 1;
  int hrB = slot0b + rB; hrB = hrB < NROWS ? hrB : NROWS - 1;
  const ushort_t* ghA = h + (size_t)hrA * HIDDEN + sA * 8;
  const ushort_t* ghB = h + (size_t)hrB * HIDDEN + sB * 8;

  const int uD = wid * 64 + lane;
  const int rD = uD >> 2, sD = (uD & 3) ^ ((rD >> 1) & 3);
  const ushort_t* gdp = wdb + ((size_t)e * DIM + (size_t)nt * BN + rD) * HIDDEN + sD * 8;

  ushort_t* ldsAA = AsL + (size_t)(wid * 128) * 8;
  ushort_t* ldsAB = AsL + (size_t)(wid * 128 + 64) * 8;
  ushort_t* ldsD  = DsL + (size_t)(wid * 64) * 8;

  f32x4 acc[4][2];
#pragma unroll
  for (int i = 0; i < 4; ++i)
#pragma unroll
    for (int j = 0; j < 2; ++j) acc[i][j] = (f32x4)0.f;

  for (int k0 = 0; k0 < HIDDEN; k0 += BK) {
    GLDS16(ghA + k0, ldsAA);
    GLDS16(ghB + k0, ldsAB);
    GLDS16(gdp + k0, ldsD);
    __syncthreads();

    bf16x8 b0 = ldt(DsL, wn * 32 + fr, kg);
    bf16x8 b1 = ldt(DsL, wn * 32 + 16 + fr, kg);
#pragma unroll
    for (int mf = 0; mf < 4; ++mf) {
      bf16x8 a = ldt(AsL, wm * 64 + mf * 16 + fr, kg);
      acc[mf][0] = mfma16(a, b0, acc[mf][0]);
      acc[mf][1] = mfma16(a, b1, acc[mf][1]);
    }
    __syncthreads();
  }

  const int nbase = nt * BN + wn * 32;
#pragma unroll
  for (int mf = 0; mf < 4; ++mf) {
#pragma unroll
    for (int r = 0; r < 4; ++r) {
      int ml = wm * 64 + mf * 16 + kg * 4 + r;
      int m  = mt * BM + ml;
      if (m < count) {
        size_t row = (size_t)(slot0b + ml);   // = offsets[e] + m
#pragma unroll
        for (int nf = 0; nf < 2; ++nf) {
          y[row * DIM + nbase + nf * 16 + fr] = acc[mf][nf][r];
        }
      }
    }
  }
}

// TIER1 variant: validated atomic epilogue into out (kept as fallback).
__global__ __launch_bounds__(256) void stage2_kernel(
    const ushort_t* __restrict__ h, const ushort_t* __restrict__ wdb,
    const int* __restrict__ counts, const int* __restrict__ offsets,
    const int* __restrict__ token_list, const float* __restrict__ weight_list,
    float* __restrict__ out) {
  const int e  = blockIdx.z;
  const int mt = blockIdx.y;
  const int nt = blockIdx.x;
  const int count = counts[e];
  if (mt * BM >= count) return;

  __shared__ __align__(16) ushort_t AsL[BM * 32];
  __shared__ __align__(16) ushort_t DsL[BN * 32];
  __shared__ int   toks[BM];
  __shared__ float wts[BM];

  const int t = threadIdx.x;
  if (t < BM) {
    int m  = mt * BM + t;
    int mc = m < count ? m : count - 1;
    toks[t] = token_list[e * CAP + mc];
    wts[t]  = weight_list[e * CAP + mc];
  }
  __syncthreads();

  const int wid  = t >> 6;
  const int lane = t & 63;
  const int wm   = wid & 1;
  const int wn   = wid >> 1;
  const int fr   = lane & 15;
  const int kg   = lane >> 4;

  const int slot0b = offsets[e] + mt * BM;

  const int uA = wid * 128 + lane;
  const int uB = uA + 64;
  const int rA = uA >> 2, sA = (uA & 3) ^ ((rA >> 1) & 3);
  const int rB = uB >> 2, sB = (uB & 3) ^ ((rB >> 1) & 3);
  int hrA = slot0b + rA; hrA = hrA < NROWS ? hrA : NROWS - 1;
  int hrB = slot0b + rB; hrB = hrB < NROWS ? hrB : NROWS - 1;
  const ushort_t* ghA = h + (size_t)hrA * HIDDEN + sA * 8;
  const ushort_t* ghB = h + (size_t)hrB * HIDDEN + sB * 8;

  const int uD = wid * 64 + lane;
  const int rD = uD >> 2, sD = (uD & 3) ^ ((rD >> 1) & 3);
  const ushort_t* gdp = wdb + ((size_t)e * DIM + (size_t)nt * BN + rD) * HIDDEN + sD * 8;

  ushort_t* ldsAA = AsL + (size_t)(wid * 128) * 8;
  ushort_t* ldsAB = AsL + (size_t)(wid * 128 + 64) * 8;
  ushort_t* ldsD  = DsL + (size_t)(wid * 64) * 8;

  f32x4 acc[4][2];
#pragma unroll
  for (int i = 0; i < 4; ++i)
#pragma unroll
    for (int j = 0; j < 2; ++j) acc[i][j] = (f32x4)0.f;

  for (int k0 = 0; k0 < HIDDEN; k0 += BK) {
    GLDS16(ghA + k0, ldsAA);
    GLDS16(ghB + k0, ldsAB);
    GLDS16(gdp + k0, ldsD);
    __syncthreads();

    bf16x8 b0 = ldt(DsL, wn * 32 + fr, kg);
    bf16x8 b1 = ldt(DsL, wn * 32 + 16 + fr, kg);
#pragma unroll
    for (int mf = 0; mf < 4; ++mf) {
      bf16x8 a = ldt(AsL, wm * 64 + mf * 16 + fr, kg);
      acc[mf][0] = mfma16(a, b0, acc[mf][0]);
      acc[mf][1] = mfma16(a, b1, acc[mf][1]);
    }
    __syncthreads();
  }

  const int nbase = nt * BN + wn * 32;
#pragma unroll
  for (int mf = 0; mf < 4; ++mf) {
#pragma unroll
    for (int r = 0; r < 4; ++r) {
      int ml = wm * 64 + mf * 16 + kg * 4 + r;
      int m  = mt * BM + ml;
      if (m < count) {
        int   tok = toks[ml];
        float w   = wts[ml];
        size_t o  = (size_t)tok * DIM + nbase;
#pragma unroll
        for (int nf = 0; nf < 2; ++nf) {
          atomicAdd(&out[o + nf * 16 + fr], acc[mf][nf][r] * w);
        }
      }
    }
  }
}

// ---------------- final combine: out[tok] = w0*y[slot0] + w1*y[slot1] ----------------
__global__ __launch_bounds__(256) void combine_kernel(
    const float* __restrict__ y, const int* __restrict__ tpair,
    const float* __restrict__ weight_list, const int* __restrict__ offsets,
    float* __restrict__ out) {
  const int tok = blockIdx.x;
  const int v0 = tpair[tok * 2 + 0];
  const int v1 = tpair[tok * 2 + 1];
  const float w0 = weight_list[v0];
  const float w1 = weight_list[v1];
  const int s0 = offsets[v0 >> 13] + (v0 & (CAP - 1));
  const int s1 = offsets[v1 >> 13] + (v1 & (CAP - 1));
  const int d = threadIdx.x * 4;
  float4 a = *reinterpret_cast<const float4*>(y + (size_t)s0 * DIM + d);
  float4 b = *reinterpret_cast<const float4*>(y + (size_t)s1 * DIM + d);
  float4 o;
  o.x = w0 * a.x + w1 * b.x;
  o.y = w0 * a.y + w1 * b.y;
  o.z = w0 * a.z + w1 * b.z;
  o.w = w0 * a.w + w1 * b.w;
  *reinterpret_cast<float4*>(out + (size_t)tok * DIM + d) = o;
}

// ================= fallback path (fp32 weights in-loop, validated in R2) =================
__global__ __launch_bounds__(256) void stage1_f32w(
    const float* __restrict__ x, const float* __restrict__ Wgate,
    const float* __restrict__ Wup, const int* __restrict__ counts,
    const int* __restrict__ offsets, const int* __restrict__ token_list,
    ushort_t* __restrict__ h) {
  const int e  = blockIdx.z;
  const int mt = blockIdx.y;
  const int nt = blockIdx.x;
  const int count = counts[e];
  if (mt * BM >= count) return;

  __shared__ __align__(16) ushort_t Xs[BM][LDP];
  __shared__ __align__(16) ushort_t Gs[BN][LDP];
  __shared__ __align__(16) ushort_t Us[BN][LDP];
  __shared__ int toks[BM];

  const int t = threadIdx.x;
  if (t < BM) {
    int m = mt * BM + t;
    toks[t] = token_list[e * CAP + (m < count ? m : count - 1)];
  }
  __syncthreads();

  const float* Wg = Wgate + (size_t)e * HIDDEN * DIM + (size_t)(nt * BN) * DIM;
  const float* Wu = Wup   + (size_t)e * HIDDEN * DIM + (size_t)(nt * BN) * DIM;

  const int wid  = t >> 6;
  const int lane = t & 63;
  const int wm   = wid & 1;
  const int wn   = wid >> 1;
  const int fr   = lane & 15;
  const int kg   = lane >> 4;

  f32x4 accg[4][2], accu[4][2];
#pragma unroll
  for (int i = 0; i < 4; ++i)
#pragma unroll
    for (int j = 0; j < 2; ++j) { accg[i][j] = (f32x4)0.f; accu[i][j] = (f32x4)0.f; }

  const int sr = t >> 2;
  const int sc = (t & 3) * 8;

  const int tok0 = toks[sr];
  const int tok1 = toks[sr + 64];
  const float* xp0 = x + (size_t)tok0 * DIM + sc;
  const float* xp1 = x + (size_t)tok1 * DIM + sc;
  const float* gp  = Wg + (size_t)sr * DIM + sc;
  const float* up  = Wu + (size_t)sr * DIM + sc;

  for (int k0 = 0; k0 < DIM; k0 += BK) {
    float4 a0 = *reinterpret_cast<const float4*>(xp0 + k0);
    float4 a1 = *reinterpret_cast<const float4*>(xp0 + k0 + 4);
    float4 b0 = *reinterpret_cast<const float4*>(xp1 + k0);
    float4 b1 = *reinterpret_cast<const float4*>(xp1 + k0 + 4);
    float4 g0 = *reinterpret_cast<const float4*>(gp + k0);
    float4 g1 = *reinterpret_cast<const float4*>(gp + k0 + 4);
    float4 u0 = *reinterpret_cast<const float4*>(up + k0);
    float4 u1 = *reinterpret_cast<const float4*>(up + k0 + 4);
    st8(&Xs[sr][sc],      a0, a1);
    st8(&Xs[sr + 64][sc], b0, b1);
    st8(&Gs[sr][sc],      g0, g1);
    st8(&Us[sr][sc],      u0, u1);
    __syncthreads();

    bf16x8 bg0 = ldb(&Gs[wn * 32 + fr][kg * 8]);
    bf16x8 bg1 = ldb(&Gs[wn * 32 + 16 + fr][kg * 8]);
    bf16x8 bu0 = ldb(&Us[wn * 32 + fr][kg * 8]);
    bf16x8 bu1 = ldb(&Us[wn * 32 + 16 + fr][kg * 8]);
#pragma unroll
    for (int mf = 0; mf < 4; ++mf) {
      bf16x8 a = ldb(&Xs[wm * 64 + mf * 16 + fr][kg * 8]);
      accg[mf][0] = mfma16(a, bg0, accg[mf][0]);
      accg[mf][1] = mfma16(a, bg1, accg[mf][1]);
      accu[mf][0] = mfma16(a, bu0, accu[mf][0]);
      accu[mf][1] = mfma16(a, bu1, accu[mf][1]);
    }
    __syncthreads();
  }

  const size_t slot0 = (size_t)offsets[e];
  const int nbase = nt * BN + wn * 32;
#pragma unroll
  for (int mf = 0; mf < 4; ++mf) {
#pragma unroll
    for (int r = 0; r < 4; ++r) {
      int ml = wm * 64 + mf * 16 + kg * 4 + r;
      int m  = mt * BM + ml;
      if (m < count) {
        size_t rowoff = (slot0 + m) * (size_t)HIDDEN + nbase;
#pragma unroll
        for (int nf = 0; nf < 2; ++nf) {
          float g  = accg[mf][nf][r];
          float uu = accu[mf][nf][r];
          float hv = g / (1.f + __expf(-g)) * uu;
          h[rowoff + nf * 16 + fr] = cvt_bf16(hv);
        }
      }
    }
  }
}

__global__ __launch_bounds__(256) void stage2_f32w(
    const ushort_t* __restrict__ h, const float* __restrict__ Wdown,
    const int* __restrict__ counts, const int* __restrict__ offsets,
    const int* __restrict__ token_list, const float* __restrict__ weight_list,
    float* __restrict__ out) {
  const int e  = blockIdx.z;
  const int mt = blockIdx.y;
  const int nt = blockIdx.x;
  const int count = counts[e];
  if (mt * BM >= count) return;

  __shared__ __align__(16) ushort_t As[BM][LDP];
  __shared__ __align__(16) ushort_t Ds[BN][LDP];
  __shared__ int   toks[BM];
  __shared__ float wts[BM];

  const int t = threadIdx.x;
  if (t < BM) {
    int m  = mt * BM + t;
    int mc = m < count ? m : count - 1;
    toks[t] = token_list[e * CAP + mc];
    wts[t]  = weight_list[e * CAP + mc];
  }
  __syncthreads();

  const float* Wd = Wdown + (size_t)e * DIM * HIDDEN + (size_t)(nt * BN) * HIDDEN;
  const int slot0b = offsets[e] + mt * BM;

  const int wid  = t >> 6;
  const int lane = t & 63;
  const int wm   = wid & 1;
  const int wn   = wid >> 1;
  const int fr   = lane & 15;
  const int kg   = lane >> 4;

  f32x4 acc[4][2];
#pragma unroll
  for (int i = 0; i < 4; ++i)
#pragma unroll
    for (int j = 0; j < 2; ++j) acc[i][j] = (f32x4)0.f;

  const int sr = t >> 2;
  const int sc = (t & 3) * 8;

  int r0 = slot0b + sr;       r0 = r0 < NROWS ? r0 : NROWS - 1;
  int r1 = slot0b + sr + 64;  r1 = r1 < NROWS ? r1 : NROWS - 1;
  const ushort_t* hp0 = h + (size_t)r0 * HIDDEN + sc;
  const ushort_t* hp1 = h + (size_t)r1 * HIDDEN + sc;
  const float*    dp  = Wd + (size_t)sr * HIDDEN + sc;

  for (int k0 = 0; k0 < HIDDEN; k0 += BK) {
    s16x8 ha = *reinterpret_cast<const s16x8*>(hp0 + k0);
    s16x8 hb = *reinterpret_cast<const s16x8*>(hp1 + k0);
    float4 d0 = *reinterpret_cast<const float4*>(dp + k0);
    float4 d1 = *reinterpret_cast<const float4*>(dp + k0 + 4);
    *reinterpret_cast<s16x8*>(&As[sr][sc])      = ha;
    *reinterpret_cast<s16x8*>(&As[sr + 64][sc]) = hb;
    st8(&Ds[sr][sc], d0, d1);
    __syncthreads();

    bf16x8 b0 = ldb(&Ds[wn * 32 + fr][kg * 8]);
    bf16x8 b1 = ldb(&Ds[wn * 32 + 16 + fr][kg * 8]);
#pragma unroll
    for (int mf = 0; mf < 4; ++mf) {
      bf16x8 a = ldb(&As[wm * 64 + mf * 16 + fr][kg * 8]);
      acc[mf][0] = mfma16(a, b0, acc[mf][0]);
      acc[mf][1] = mfma16(a, b1, acc[mf][1]);
    }
    __syncthreads();
  }

  const int nbase = nt * BN + wn * 32;
#pragma unroll
  for (int mf = 0; mf < 4; ++mf) {
#pragma unroll
    for (int r = 0; r < 4; ++r) {
      int ml = wm * 64 + mf * 16 + kg * 4 + r;
      int m  = mt * BM + ml;
      if (m < count) {
        int   tok = toks[ml];
        float w   = wts[ml];
        size_t o  = (size_t)tok * DIM + nbase;
#pragma unroll
        for (int nf = 0; nf < 2; ++nf) {
          atomicAdd(&out[o + nf * 16 + fr], acc[mf][nf][r] * w);
        }
      }
    }
  }
}

// ---------------- launch ----------------
extern "C" void kernel_launch(void* const* d_in, const int* in_sizes, int n_in,
                              void* d_out, int out_size, void* d_ws, size_t ws_size,
                              hipStream_t stream) {
  const float* x     = (const float*)d_in[0];
  const float* wg    = (const float*)d_in[1];
  const float* bg    = (const float*)d_in[2];
  const float* Wgate = (const float*)d_in[3];
  const float* Wup   = (const float*)d_in[4];
  const float* Wdown = (const float*)d_in[5];
  float* out = (float*)d_out;

  char* ws = (char*)d_ws;
  int*      counts      = (int*)(ws + WS_COUNTS);
  int*      offsets     = (int*)(ws + WS_OFFSETS);
  int*      tpair       = (int*)(ws + WS_TPAIR);
  int*      token_list  = (int*)(ws + WS_TOKENS);
  float*    weight_list = (float*)(ws + WS_WEIGHTS);
  ushort_t* h           = (ushort_t*)(ws + WS_H);

  hipMemsetAsync(counts, 0, NE * sizeof(int), stream);

  gating_kernel<<<NTOK / 4, 256, 0, stream>>>(x, wg, bg, counts, token_list,
                                              weight_list, tpair);
  prefix_kernel<<<1, 64, 0, stream>>>(counts, offsets);

  const bool tier1 = ws_size >= WS_T1_END;   // full bf16 path fits (~286 MB)
  const bool tier3 = ws_size >= WS_T3_END;   // + y rows fit (~353 MB)

  if (tier1) {
    ushort_t* xb  = (ushort_t*)(ws + WS_XB);
    ushort_t* wA  = (ushort_t*)(ws + WS_WA);    // Wgate during stage1, Wdown after
    ushort_t* wub = (ushort_t*)(ws + WS_WUB);

    long w8 = (long)NE * HIDDEN * DIM / 8;
    long x8 = (long)NTOK * DIM / 8;
    cvt_kernel<<<8192, 256, 0, stream>>>(Wgate, wA, w8);
    cvt_kernel<<<8192, 256, 0, stream>>>(Wup,   wub, w8);
    cvt_kernel<<<4096, 256, 0, stream>>>(x,     xb,  x8);

    stage1_kernel<<<dim3(HIDDEN / BN, CAP / BM, NE), 256, 0, stream>>>(
        xb, wA, wub, counts, offsets, token_list, h);

    // stage1 no longer reads wA -> reuse the buffer for Wdown (stream-ordered)
    cvt_kernel<<<8192, 256, 0, stream>>>(Wdown, wA, w8);

    if (tier3) {
      float* y = (float*)(ws + WS_Y);
      stage2_y_kernel<<<dim3(DIM / BN, CAP / BM, NE), 256, 0, stream>>>(
          h, wA, counts, offsets, y);
      combine_kernel<<<NTOK, 256, 0, stream>>>(y, tpair, weight_list, offsets, out);
    } else {
      hipMemsetAsync(out, 0, (size_t)NTOK * DIM * sizeof(float), stream);
      stage2_kernel<<<dim3(DIM / BN, CAP / BM, NE), 256, 0, stream>>>(
          h, wA, counts, offsets, token_list, weight_list, out);
    }
  } else {
    hipMemsetAsync(out, 0, (size_t)NTOK * DIM * sizeof(float), stream);
    stage1_f32w<<<dim3(HIDDEN / BN, CAP / BM, NE), 256, 0, stream>>>(
        x, Wgate, Wup, counts, offsets, token_list, h);
    stage2_f32w<<<dim3(DIM / BN, CAP / BM, NE), 256, 0, stream>>>(
        h, Wdown, counts, offsets, token_list, weight_list, out);
  }
}